// Round 1
// baseline (3127.807 us; speedup 1.0000x reference)
//
#include <hip/hip_runtime.h>
#include <stdint.h>

#define T_ROWS 1024
#define NVIS   4096
#define NHID   2048
#define KGIBBS 25   // K is a static python int (25) in setup_inputs

typedef __attribute__((ext_vector_type(8))) short short8;
typedef __attribute__((ext_vector_type(4))) float f32x4;
typedef __attribute__((ext_vector_type(4))) unsigned short us4;

#define AS1CV(p) ((const __attribute__((address_space(1))) void*)(p))
#define AS3V(p)  ((__attribute__((address_space(3))) void*)(p))

__device__ inline unsigned short f2bf(float f) {
  union { float f; uint32_t u; } c; c.f = f;
  uint32_t u = c.u;
  uint32_t r = (u + 0x7FFFu + ((u >> 16) & 1u)) >> 16;
  return (unsigned short)r;
}

__device__ inline float bf2f(unsigned short s) {
  union { uint32_t u; float f; } c; c.u = ((uint32_t)s) << 16;
  return c.f;
}

// deterministic counter-based uniform in [0,1): murmur3 fmix64 of (phase, idx)
__device__ inline float rng_u(uint32_t phase, uint32_t idx) {
  uint64_t z = (((uint64_t)phase) << 42) | (uint64_t)idx;   // idx < 2^22, phase < 64
  z ^= z >> 33; z *= 0xFF51AFD7ED558CCDULL;
  z ^= z >> 33; z *= 0xC4CEB9FE1A85EC53ULL;
  z ^= z >> 33;
  return (float)(uint32_t)(z >> 40) * (1.0f / 16777216.0f); // 24-bit mantissa
}

// ---------------------------------------------------------------------------
// W prep: fp32 -> bf16, plus transposed copy (so both GEMM directions are NT)
// ---------------------------------------------------------------------------
__global__ void __launch_bounds__(256) prep_w(const float* __restrict__ w,
                                              unsigned short* __restrict__ Wb,
                                              unsigned short* __restrict__ WTb)
{
  __shared__ unsigned short tile[64][72];   // padded to dodge bank conflicts
  const int bi  = blockIdx.x * 64;   // NV offset
  const int bh0 = blockIdx.y * 64;   // NH offset
  const int t   = threadIdx.x;
  const int rr  = t >> 4;            // 0..15
  const int cc  = (t & 15) * 4;      // 0,4,..,60
#pragma unroll
  for (int p = 0; p < 4; ++p) {
    int row = p * 16 + rr;
    const float4 v = *(const float4*)&w[(size_t)(bh0 + row) * NVIS + bi + cc];
    unsigned short b0 = f2bf(v.x), b1 = f2bf(v.y), b2 = f2bf(v.z), b3 = f2bf(v.w);
    us4 pk; pk.x = b0; pk.y = b1; pk.z = b2; pk.w = b3;
    *(us4*)&Wb[(size_t)(bh0 + row) * NVIS + bi + cc] = pk;
    tile[cc + 0][row] = b0; tile[cc + 1][row] = b1;
    tile[cc + 2][row] = b2; tile[cc + 3][row] = b3;
  }
  __syncthreads();
#pragma unroll
  for (int p = 0; p < 4; ++p) {
    int row = p * 16 + rr;           // i-local
    us4 pk;
    pk.x = tile[row][cc + 0]; pk.y = tile[row][cc + 1];
    pk.z = tile[row][cc + 2]; pk.w = tile[row][cc + 3];
    *(us4*)&WTb[(size_t)(bi + row) * NHID + bh0 + cc] = pk;
  }
}

// x (fp32 0/1) -> bf16 V buffer
__global__ void __launch_bounds__(256) xcvt(const float* __restrict__ x,
                                            unsigned short* __restrict__ Vb)
{
  int i = blockIdx.x * 256 + threadIdx.x;   // grid covers T*NV/4 exactly
  const float4 v = ((const float4*)x)[i];
  us4 pk; pk.x = f2bf(v.x); pk.y = f2bf(v.y); pk.z = f2bf(v.z); pk.w = f2bf(v.w);
  ((us4*)Vb)[i] = pk;
}

// sum over all (t,i) of V[t,i]*bv[i] -> per-block partials
__global__ void __launch_bounds__(256) bvdot(const unsigned short* __restrict__ V,
                                             const float* __restrict__ bv,
                                             float* __restrict__ part)
{
  float local = 0.f;
  for (int v = blockIdx.x * 256 + threadIdx.x; v < T_ROWS * NVIS / 4; v += 256 * 256) {
    int col4 = (v & (NVIS / 4 - 1)) * 4;
    us4 a = ((const us4*)V)[v];
    float4 b = *(const float4*)&bv[col4];
    local += bf2f(a.x) * b.x + bf2f(a.y) * b.y + bf2f(a.z) * b.z + bf2f(a.w) * b.w;
  }
#pragma unroll
  for (int off = 32; off > 0; off >>= 1) local += __shfl_down(local, off, 64);
  __shared__ float red[4];
  if ((threadIdx.x & 63) == 0) red[threadIdx.x >> 6] = local;
  __syncthreads();
  if (threadIdx.x == 0) part[blockIdx.x] = red[0] + red[1] + red[2] + red[3];
}

// ---------------------------------------------------------------------------
// GEMM: C[M,N] = A[M,K] * B^T where B is stored [N][K] row-major (NT layout).
// 128x128 tile, BK=64, 4 waves (2x2), 16x16x32 bf16 MFMA.
// MODE 0: out = bernoulli(sigmoid(z + bias))  (bf16 0/1)
// MODE 1: per-block partial of sum softplus(z + bias)
// ---------------------------------------------------------------------------
template <int MODE>
__global__ void __launch_bounds__(256)
rbm_gemm(const unsigned short* __restrict__ A, int lda,
         const unsigned short* __restrict__ B, int ldb,
         const float* __restrict__ bias,
         unsigned short* __restrict__ C, int ldc,
         float* __restrict__ fpart,
         int kdim, uint32_t phase)
{
  __shared__ __align__(16) char lds[32768];
  char* lA = lds;
  char* lB = lds + 16384;

  const int tid  = threadIdx.x;
  const int lane = tid & 63;
  const int wv   = tid >> 6;
  const int wr   = wv >> 1, wc = wv & 1;
  const int bm0  = blockIdx.y * 128;
  const int bn0  = blockIdx.x * 128;

  // staging: thread covers 4 chunks of A and 4 of B; 16B each.
  // LDS linear chunk L = j*256+tid -> (row = L>>3, c = L&7); source col-chunk = c ^ (row&7)
  const int sRow = tid >> 3;                                  // 0..31
  const int sCol = (((tid & 7) ^ ((tid >> 3) & 7)) * 8);      // swizzled source col (elems)
  const unsigned short* gA = A + (size_t)(bm0 + sRow) * lda + sCol;
  const unsigned short* gB = B + (size_t)(bn0 + sRow) * ldb + sCol;

  f32x4 acc[4][4];
#pragma unroll
  for (int m = 0; m < 4; ++m)
#pragma unroll
    for (int n = 0; n < 4; ++n) acc[m][n] = (f32x4)0.0f;

  const int lr = lane & 15;
  const int lq = lane >> 4;

  const int nkt = kdim >> 6;
  for (int kt = 0; kt < nkt; ++kt) {
    __syncthreads();
    const unsigned short* a0 = gA + kt * 64;
    const unsigned short* b0 = gB + kt * 64;
#pragma unroll
    for (int j = 0; j < 4; ++j)
      __builtin_amdgcn_global_load_lds(AS1CV(a0 + (size_t)j * 32 * lda),
                                       AS3V(lA + (j * 256 + tid) * 16), 16, 0, 0);
#pragma unroll
    for (int j = 0; j < 4; ++j)
      __builtin_amdgcn_global_load_lds(AS1CV(b0 + (size_t)j * 32 * ldb),
                                       AS3V(lB + (j * 256 + tid) * 16), 16, 0, 0);
    __syncthreads();

#pragma unroll
    for (int ks = 0; ks < 2; ++ks) {
      short8 af[4], bf_[4];
#pragma unroll
      for (int m = 0; m < 4; ++m) {
        int row = wr * 64 + m * 16 + lr;
        int off = row * 128 + (((ks * 4 + lq) ^ (row & 7)) * 16);
        af[m] = *(const short8*)(lA + off);
      }
#pragma unroll
      for (int n = 0; n < 4; ++n) {
        int row = wc * 64 + n * 16 + lr;
        int off = row * 128 + (((ks * 4 + lq) ^ (row & 7)) * 16);
        bf_[n] = *(const short8*)(lB + off);
      }
#pragma unroll
      for (int m = 0; m < 4; ++m)
#pragma unroll
        for (int n = 0; n < 4; ++n)
          acc[m][n] = __builtin_amdgcn_mfma_f32_16x16x32_bf16(af[m], bf_[n], acc[m][n], 0, 0, 0);
    }
  }

  if (MODE == 0) {
    // fused sigmoid + bernoulli sample -> bf16 {0,1}
#pragma unroll
    for (int n = 0; n < 4; ++n) {
      int col = bn0 + wc * 64 + n * 16 + lr;
      float bv_ = bias[col];
#pragma unroll
      for (int m = 0; m < 4; ++m) {
        int row0 = bm0 + wr * 64 + m * 16 + lq * 4;
#pragma unroll
        for (int j = 0; j < 4; ++j) {
          int row = row0 + j;
          float z = acc[m][n][j] + bv_;
          float p = 1.0f / (1.0f + __expf(-z));
          float u = rng_u(phase, (uint32_t)(row * ldc + col));
          C[(size_t)row * ldc + col] = (u < p) ? (unsigned short)0x3F80 : (unsigned short)0;
        }
      }
    }
  } else {
    // free-energy partial: sum softplus(z + bias)
    float local = 0.0f;
#pragma unroll
    for (int n = 0; n < 4; ++n) {
      int col = bn0 + wc * 64 + n * 16 + lr;
      float bv_ = bias[col];
#pragma unroll
      for (int m = 0; m < 4; ++m) {
#pragma unroll
        for (int j = 0; j < 4; ++j) {
          float z = acc[m][n][j] + bv_;
          local += fmaxf(z, 0.0f) + log1pf(expf(-fabsf(z)));
        }
      }
    }
#pragma unroll
    for (int off = 32; off > 0; off >>= 1) local += __shfl_down(local, off, 64);
    __shared__ float red[4];
    if (lane == 0) red[wv] = local;
    __syncthreads();
    if (tid == 0) fpart[blockIdx.y * gridDim.x + blockIdx.x] = red[0] + red[1] + red[2] + red[3];
  }
}

// final: cost = (Sv + v.bv - Sx - x.bv) / T, double-precision reduce
__global__ void __launch_bounds__(256) finalize(const float* __restrict__ pFx,
                                                const float* __restrict__ pFv,
                                                const float* __restrict__ pXbv,
                                                const float* __restrict__ pVbv,
                                                float* __restrict__ out)
{
  __shared__ double red[256];
  double local = 0.0;
  int t = threadIdx.x;
  for (int i = t; i < 768; i += 256) {
    if (i < 128)      local -= (double)pFx[i];
    else if (i < 256) local += (double)pFv[i - 128];
    else if (i < 512) local -= (double)pXbv[i - 256];
    else              local += (double)pVbv[i - 512];
  }
  red[t] = local;
  __syncthreads();
  for (int s = 128; s > 0; s >>= 1) {
    if (t < s) red[t] += red[t + s];
    __syncthreads();
  }
  if (t == 0) out[0] = (float)(red[0] / (double)T_ROWS);
}

extern "C" void kernel_launch(void* const* d_in, const int* in_sizes, int n_in,
                              void* d_out, int out_size, void* d_ws, size_t ws_size,
                              hipStream_t stream)
{
  const float* x  = (const float*)d_in[0];
  const float* w  = (const float*)d_in[1];
  const float* bh = (const float*)d_in[2];
  const float* bv = (const float*)d_in[3];
  // d_in[4] = K, static 25

  char* ws = (char*)d_ws;
  unsigned short* Wb  = (unsigned short*)ws;                            // 16 MB
  unsigned short* WTb = (unsigned short*)(ws + (size_t)16777216);       // 16 MB
  unsigned short* Vb  = (unsigned short*)(ws + (size_t)33554432);       //  8 MB
  unsigned short* Hb  = (unsigned short*)(ws + (size_t)41943040);       //  4 MB
  float* pFx  = (float*)(ws + (size_t)46137344);
  float* pFv  = pFx + 128;
  float* pXbv = pFv + 128;
  float* pVbv = pXbv + 256;

  prep_w<<<dim3(NVIS / 64, NHID / 64), 256, 0, stream>>>(w, Wb, WTb);
  xcvt<<<(T_ROWS * NVIS / 4) / 256, 256, 0, stream>>>(x, Vb);

  // F(x) softplus part: z = x @ W^T + bh   [1024 x 2048]
  rbm_gemm<1><<<dim3(NHID / 128, T_ROWS / 128), 256, 0, stream>>>(
      Vb, NVIS, Wb, NVIS, bh, nullptr, 0, pFx, NVIS, 0u);
  bvdot<<<256, 256, 0, stream>>>(Vb, bv, pXbv);

  for (int k = 0; k < KGIBBS; ++k) {
    // h ~ Bern(sigmoid(v @ W^T + bh))  [1024 x 2048]
    rbm_gemm<0><<<dim3(NHID / 128, T_ROWS / 128), 256, 0, stream>>>(
        Vb, NVIS, Wb, NVIS, bh, Hb, NHID, nullptr, NVIS, (uint32_t)(2 * k));
    // v ~ Bern(sigmoid(h @ W + bv))    [1024 x 4096]
    rbm_gemm<0><<<dim3(NVIS / 128, T_ROWS / 128), 256, 0, stream>>>(
        Hb, NHID, WTb, NHID, bv, Vb, NVIS, nullptr, NHID, (uint32_t)(2 * k + 1));
  }

  // F(v_o) softplus part
  rbm_gemm<1><<<dim3(NHID / 128, T_ROWS / 128), 256, 0, stream>>>(
      Vb, NVIS, Wb, NVIS, bh, nullptr, 0, pFv, NVIS, 0u);
  bvdot<<<256, 256, 0, stream>>>(Vb, bv, pVbv);

  finalize<<<1, 256, 0, stream>>>(pFx, pFv, pXbv, pVbv, (float*)d_out);
}

// Round 2
// 1846.974 us; speedup vs baseline: 1.6935x; 1.6935x over previous
//
#include <hip/hip_runtime.h>
#include <stdint.h>

#define T_ROWS 1024
#define NVIS   4096
#define NHID   2048
#define KGIBBS 25   // K is a static python int (25) in setup_inputs

typedef __attribute__((ext_vector_type(8))) short short8;
typedef __attribute__((ext_vector_type(4))) float f32x4;
typedef __attribute__((ext_vector_type(4))) unsigned short us4;

#define AS1CV(p) ((const __attribute__((address_space(1))) void*)(p))
#define AS3V(p)  ((__attribute__((address_space(3))) void*)(p))

__device__ inline unsigned short f2bf(float f) {
  union { float f; uint32_t u; } c; c.f = f;
  uint32_t u = c.u;
  uint32_t r = (u + 0x7FFFu + ((u >> 16) & 1u)) >> 16;
  return (unsigned short)r;
}

__device__ inline float bf2f(unsigned short s) {
  union { uint32_t u; float f; } c; c.u = ((uint32_t)s) << 16;
  return c.f;
}

// deterministic counter-based uniform in [0,1): murmur3 fmix64 of (phase, idx)
__device__ inline float rng_u(uint32_t phase, uint32_t idx) {
  uint64_t z = (((uint64_t)phase) << 42) | (uint64_t)idx;
  z ^= z >> 33; z *= 0xFF51AFD7ED558CCDULL;
  z ^= z >> 33; z *= 0xC4CEB9FE1A85EC53ULL;
  z ^= z >> 33;
  return (float)(uint32_t)(z >> 40) * (1.0f / 16777216.0f);
}

// ---------------------------------------------------------------------------
// W prep: fp32 -> bf16, plus transposed copy (so both GEMM directions are NT)
// ---------------------------------------------------------------------------
__global__ void __launch_bounds__(256) prep_w(const float* __restrict__ w,
                                              unsigned short* __restrict__ Wb,
                                              unsigned short* __restrict__ WTb)
{
  __shared__ unsigned short tile[64][72];
  const int bi  = blockIdx.x * 64;
  const int bh0 = blockIdx.y * 64;
  const int t   = threadIdx.x;
  const int rr  = t >> 4;
  const int cc  = (t & 15) * 4;
#pragma unroll
  for (int p = 0; p < 4; ++p) {
    int row = p * 16 + rr;
    const float4 v = *(const float4*)&w[(size_t)(bh0 + row) * NVIS + bi + cc];
    unsigned short b0 = f2bf(v.x), b1 = f2bf(v.y), b2 = f2bf(v.z), b3 = f2bf(v.w);
    us4 pk; pk.x = b0; pk.y = b1; pk.z = b2; pk.w = b3;
    *(us4*)&Wb[(size_t)(bh0 + row) * NVIS + bi + cc] = pk;
    tile[cc + 0][row] = b0; tile[cc + 1][row] = b1;
    tile[cc + 2][row] = b2; tile[cc + 3][row] = b3;
  }
  __syncthreads();
#pragma unroll
  for (int p = 0; p < 4; ++p) {
    int row = p * 16 + rr;
    us4 pk;
    pk.x = tile[row][cc + 0]; pk.y = tile[row][cc + 1];
    pk.z = tile[row][cc + 2]; pk.w = tile[row][cc + 3];
    *(us4*)&WTb[(size_t)(bi + row) * NHID + bh0 + cc] = pk;
  }
}

__global__ void __launch_bounds__(256) xcvt(const float* __restrict__ x,
                                            unsigned short* __restrict__ Vb)
{
  int i = blockIdx.x * 256 + threadIdx.x;
  const float4 v = ((const float4*)x)[i];
  us4 pk; pk.x = f2bf(v.x); pk.y = f2bf(v.y); pk.z = f2bf(v.z); pk.w = f2bf(v.w);
  ((us4*)Vb)[i] = pk;
}

__global__ void __launch_bounds__(256) bvdot(const unsigned short* __restrict__ V,
                                             const float* __restrict__ bv,
                                             float* __restrict__ part)
{
  float local = 0.f;
  for (int v = blockIdx.x * 256 + threadIdx.x; v < T_ROWS * NVIS / 4; v += 256 * 256) {
    int col4 = (v & (NVIS / 4 - 1)) * 4;
    us4 a = ((const us4*)V)[v];
    float4 b = *(const float4*)&bv[col4];
    local += bf2f(a.x) * b.x + bf2f(a.y) * b.y + bf2f(a.z) * b.z + bf2f(a.w) * b.w;
  }
#pragma unroll
  for (int off = 32; off > 0; off >>= 1) local += __shfl_down(local, off, 64);
  __shared__ float red[4];
  if ((threadIdx.x & 63) == 0) red[threadIdx.x >> 6] = local;
  __syncthreads();
  if (threadIdx.x == 0) part[blockIdx.x] = red[0] + red[1] + red[2] + red[3];
}

// ---------------------------------------------------------------------------
// GEMM: C[M,N] = A[M,K] * B^T, B stored [N][K]. BN=128 fixed, BM template.
// 512 threads = 8 waves (2 M x 4 N). Wave tile (BM/2) x 32.
// Double-buffered LDS, stage(next) issued before compute(cur), one barrier/iter.
// MODE 0: C = bernoulli(sigmoid(z + bias)) bf16 {0,1}
// MODE 1: fpart[block] = sum softplus(z + bias)
// ---------------------------------------------------------------------------
template <int MODE, int BM>
__global__ void __launch_bounds__(512, 4)
rbm_gemm(const unsigned short* __restrict__ A, int lda,
         const unsigned short* __restrict__ B, int ldb,
         const float* __restrict__ bias,
         unsigned short* __restrict__ C, int ldc,
         float* __restrict__ fpart,
         int kdim, uint32_t phase)
{
  constexpr int MR = BM / 32;              // acc rows per wave (16x16 frags)
  constexpr int ABYTES = BM * 128;         // bytes per A k-tile
  constexpr int BUFB = ABYTES + 16384;     // per-buffer bytes (A + B)
  __shared__ __align__(16) char lds[2 * BUFB];

  const int tid  = threadIdx.x;
  const int lane = tid & 63;
  const int wv   = tid >> 6;
  const int wr   = wv >> 2;                // 0..1
  const int wc   = wv & 3;                 // 0..3
  const int lr   = lane & 15;
  const int lq   = lane >> 4;

  // XCD-chunked tile swizzle, column-major decomposition (blocks in one XCD
  // share a contiguous x-range -> shared W panels in that XCD's L2)
  const int gx = gridDim.x, gy = gridDim.y;
  const int nb = gx * gy;
  int orig = blockIdx.x + blockIdx.y * gx;
  int id = (orig & 7) * (nb >> 3) + (orig >> 3);
  int tx = id / gy;
  int ty = id - tx * gy;
  const int bm0 = ty * BM;
  const int bn0 = tx * 128;

  // staging map: LDS chunk L = j*512+tid -> row=L>>3, slot=L&7;
  // source col-chunk = slot ^ (row&7)  (row+64 preserves row&7)
  const int sRow = tid >> 3;
  const int sCol = ((tid & 7) ^ (sRow & 7)) * 8;
  const unsigned short* gA = A + (size_t)(bm0 + sRow) * lda + sCol;
  const unsigned short* gB = B + (size_t)(bn0 + sRow) * ldb + sCol;

  auto STAGE = [&](int buf, int kt) {
    char* base = lds + buf * BUFB;
    const unsigned short* a0 = gA + kt * 64;
    const unsigned short* b0 = gB + kt * 64;
    __builtin_amdgcn_global_load_lds(AS1CV(a0), AS3V(base + tid * 16), 16, 0, 0);
    if (BM == 128)
      __builtin_amdgcn_global_load_lds(AS1CV(a0 + (size_t)64 * lda),
                                       AS3V(base + (512 + tid) * 16), 16, 0, 0);
    char* bb = base + ABYTES;
    __builtin_amdgcn_global_load_lds(AS1CV(b0), AS3V(bb + tid * 16), 16, 0, 0);
    __builtin_amdgcn_global_load_lds(AS1CV(b0 + (size_t)64 * ldb),
                                     AS3V(bb + (512 + tid) * 16), 16, 0, 0);
  };

  f32x4 acc[MR][2];
#pragma unroll
  for (int m = 0; m < MR; ++m)
#pragma unroll
    for (int n = 0; n < 2; ++n) acc[m][n] = (f32x4)0.0f;

  const int nkt = kdim >> 6;
  int cur = 0;
  STAGE(0, 0);
  __syncthreads();

  for (int kt = 0; kt < nkt; ++kt) {
    if (kt + 1 < nkt) STAGE(cur ^ 1, kt + 1);   // loads fly during MFMA below
    char* base = lds + cur * BUFB;
    char* bb = base + ABYTES;
#pragma unroll
    for (int ks = 0; ks < 2; ++ks) {
      short8 af[MR], bfr[2];
#pragma unroll
      for (int m = 0; m < MR; ++m) {
        int row = wr * (BM / 2) + m * 16 + lr;
        af[m] = *(const short8*)(base + row * 128 + (((ks * 4 + lq) ^ (row & 7)) * 16));
      }
#pragma unroll
      for (int n = 0; n < 2; ++n) {
        int row = wc * 32 + n * 16 + lr;
        bfr[n] = *(const short8*)(bb + row * 128 + (((ks * 4 + lq) ^ (row & 7)) * 16));
      }
#pragma unroll
      for (int m = 0; m < MR; ++m)
#pragma unroll
        for (int n = 0; n < 2; ++n)
          acc[m][n] = __builtin_amdgcn_mfma_f32_16x16x32_bf16(af[m], bfr[n], acc[m][n], 0, 0, 0);
    }
    __syncthreads();   // drains this iter's staged loads (vmcnt) + frees buf for overwrite
    cur ^= 1;
  }

  if (MODE == 0) {
#pragma unroll
    for (int n = 0; n < 2; ++n) {
      int col = bn0 + wc * 32 + n * 16 + lr;
      float bv_ = bias[col];
#pragma unroll
      for (int m = 0; m < MR; ++m) {
        int row0 = bm0 + wr * (BM / 2) + m * 16 + lq * 4;
#pragma unroll
        for (int j = 0; j < 4; ++j) {
          int row = row0 + j;
          float z = acc[m][n][j] + bv_;
          float p = 1.0f / (1.0f + __expf(-z));
          float u = rng_u(phase, (uint32_t)(row * ldc + col));
          C[(size_t)row * ldc + col] = (u < p) ? (unsigned short)0x3F80 : (unsigned short)0;
        }
      }
    }
  } else {
    float local = 0.0f;
#pragma unroll
    for (int n = 0; n < 2; ++n) {
      int col = bn0 + wc * 32 + n * 16 + lr;
      float bv_ = bias[col];
#pragma unroll
      for (int m = 0; m < MR; ++m) {
#pragma unroll
        for (int j = 0; j < 4; ++j) {
          float z = acc[m][n][j] + bv_;
          local += fmaxf(z, 0.0f) + log1pf(expf(-fabsf(z)));
        }
      }
    }
#pragma unroll
    for (int off = 32; off > 0; off >>= 1) local += __shfl_down(local, off, 64);
    float* red = (float*)lds;              // safe: after final barrier
    __syncthreads();
    if (lane == 0) red[wv] = local;
    __syncthreads();
    if (tid == 0)
      fpart[id] = red[0] + red[1] + red[2] + red[3] + red[4] + red[5] + red[6] + red[7];
  }
}

// cost = (Sv + v.bv - Sx - x.bv) / T, double-precision reduce
__global__ void __launch_bounds__(256) finalize(const float* __restrict__ pFx,
                                                const float* __restrict__ pFv,
                                                const float* __restrict__ pXbv,
                                                const float* __restrict__ pVbv,
                                                float* __restrict__ out)
{
  __shared__ double red[256];
  double local = 0.0;
  int t = threadIdx.x;
  for (int i = t; i < 1024; i += 256) {
    if (i < 256)      local -= (double)pFx[i];
    else if (i < 512) local += (double)pFv[i - 256];
    else if (i < 768) local -= (double)pXbv[i - 512];
    else              local += (double)pVbv[i - 768];
  }
  red[t] = local;
  __syncthreads();
  for (int s = 128; s > 0; s >>= 1) {
    if (t < s) red[t] += red[t + s];
    __syncthreads();
  }
  if (t == 0) out[0] = (float)(red[0] / (double)T_ROWS);
}

extern "C" void kernel_launch(void* const* d_in, const int* in_sizes, int n_in,
                              void* d_out, int out_size, void* d_ws, size_t ws_size,
                              hipStream_t stream)
{
  const float* x  = (const float*)d_in[0];
  const float* w  = (const float*)d_in[1];
  const float* bh = (const float*)d_in[2];
  const float* bv = (const float*)d_in[3];

  char* ws = (char*)d_ws;
  unsigned short* Wb  = (unsigned short*)ws;                            // 16 MB
  unsigned short* WTb = (unsigned short*)(ws + (size_t)16777216);       // 16 MB
  unsigned short* Vb  = (unsigned short*)(ws + (size_t)33554432);       //  8 MB
  unsigned short* Hb  = (unsigned short*)(ws + (size_t)41943040);       //  4 MB
  float* pFx  = (float*)(ws + (size_t)46137344);
  float* pFv  = pFx + 256;
  float* pXbv = pFv + 256;
  float* pVbv = pXbv + 256;

  prep_w<<<dim3(NVIS / 64, NHID / 64), 256, 0, stream>>>(w, Wb, WTb);
  xcvt<<<(T_ROWS * NVIS / 4) / 256, 256, 0, stream>>>(x, Vb);

  // F(x): z = x @ W^T + bh  [1024 x 2048], BM=64 -> grid 16x16 = 256 blocks
  rbm_gemm<1, 64><<<dim3(NHID / 128, T_ROWS / 64), 512, 0, stream>>>(
      Vb, NVIS, Wb, NVIS, bh, nullptr, 0, pFx, NVIS, 0u);
  bvdot<<<256, 256, 0, stream>>>(Vb, bv, pXbv);

  for (int k = 0; k < KGIBBS; ++k) {
    // h ~ Bern(sigmoid(v @ W^T + bh))  [1024 x 2048], 256 blocks
    rbm_gemm<0, 64><<<dim3(NHID / 128, T_ROWS / 64), 512, 0, stream>>>(
        Vb, NVIS, Wb, NVIS, bh, Hb, NHID, nullptr, NVIS, (uint32_t)(2 * k));
    // v ~ Bern(sigmoid(h @ W + bv))    [1024 x 4096], 256 blocks
    rbm_gemm<0, 128><<<dim3(NVIS / 128, T_ROWS / 128), 512, 0, stream>>>(
        Hb, NHID, WTb, NHID, bv, Vb, NVIS, nullptr, NHID, (uint32_t)(2 * k + 1));
  }

  rbm_gemm<1, 64><<<dim3(NHID / 128, T_ROWS / 64), 512, 0, stream>>>(
      Vb, NVIS, Wb, NVIS, bh, nullptr, 0, pFv, NVIS, 0u);
  bvdot<<<256, 256, 0, stream>>>(Vb, bv, pVbv);

  finalize<<<1, 256, 0, stream>>>(pFx, pFv, pXbv, pVbv, (float*)d_out);
}

// Round 3
// 1276.270 us; speedup vs baseline: 2.4507x; 1.4472x over previous
//
#include <hip/hip_runtime.h>
#include <stdint.h>

#define T_ROWS 1024
#define NVIS   4096
#define NHID   2048
#define KGIBBS 25   // K is a static python int (25) in setup_inputs

typedef __attribute__((ext_vector_type(8))) short short8;
typedef __attribute__((ext_vector_type(4))) float f32x4;
typedef __attribute__((ext_vector_type(4))) unsigned short us4;

#define AS1CV(p) ((const __attribute__((address_space(1))) void*)(p))
#define AS3V(p)  ((__attribute__((address_space(3))) void*)(p))

__device__ inline unsigned short f2bf(float f) {
  union { float f; uint32_t u; } c; c.f = f;
  uint32_t u = c.u;
  uint32_t r = (u + 0x7FFFu + ((u >> 16) & 1u)) >> 16;
  return (unsigned short)r;
}

__device__ inline float bf2f(unsigned short s) {
  union { uint32_t u; float f; } c; c.u = ((uint32_t)s) << 16;
  return c.f;
}

// deterministic counter-based uniform in [0,1): murmur3 fmix64 of (phase, idx)
__device__ inline float rng_u(uint32_t phase, uint32_t idx) {
  uint64_t z = (((uint64_t)phase) << 42) | (uint64_t)idx;
  z ^= z >> 33; z *= 0xFF51AFD7ED558CCDULL;
  z ^= z >> 33; z *= 0xC4CEB9FE1A85EC53ULL;
  z ^= z >> 33;
  return (float)(uint32_t)(z >> 40) * (1.0f / 16777216.0f);
}

// ---------------------------------------------------------------------------
// W prep: fp32 -> bf16, plus transposed copy (so both GEMM directions are NT)
// ---------------------------------------------------------------------------
__global__ void __launch_bounds__(256) prep_w(const float* __restrict__ w,
                                              unsigned short* __restrict__ Wb,
                                              unsigned short* __restrict__ WTb)
{
  __shared__ unsigned short tile[64][72];
  const int bi  = blockIdx.x * 64;
  const int bh0 = blockIdx.y * 64;
  const int t   = threadIdx.x;
  const int rr  = t >> 4;
  const int cc  = (t & 15) * 4;
#pragma unroll
  for (int p = 0; p < 4; ++p) {
    int row = p * 16 + rr;
    const float4 v = *(const float4*)&w[(size_t)(bh0 + row) * NVIS + bi + cc];
    unsigned short b0 = f2bf(v.x), b1 = f2bf(v.y), b2 = f2bf(v.z), b3 = f2bf(v.w);
    us4 pk; pk.x = b0; pk.y = b1; pk.z = b2; pk.w = b3;
    *(us4*)&Wb[(size_t)(bh0 + row) * NVIS + bi + cc] = pk;
    tile[cc + 0][row] = b0; tile[cc + 1][row] = b1;
    tile[cc + 2][row] = b2; tile[cc + 3][row] = b3;
  }
  __syncthreads();
#pragma unroll
  for (int p = 0; p < 4; ++p) {
    int row = p * 16 + rr;
    us4 pk;
    pk.x = tile[row][cc + 0]; pk.y = tile[row][cc + 1];
    pk.z = tile[row][cc + 2]; pk.w = tile[row][cc + 3];
    *(us4*)&WTb[(size_t)(bi + row) * NHID + bh0 + cc] = pk;
  }
}

__global__ void __launch_bounds__(256) xcvt(const float* __restrict__ x,
                                            unsigned short* __restrict__ Vb)
{
  int i = blockIdx.x * 256 + threadIdx.x;
  const float4 v = ((const float4*)x)[i];
  us4 pk; pk.x = f2bf(v.x); pk.y = f2bf(v.y); pk.z = f2bf(v.z); pk.w = f2bf(v.w);
  ((us4*)Vb)[i] = pk;
}

__global__ void __launch_bounds__(256) bvdot(const unsigned short* __restrict__ V,
                                             const float* __restrict__ bv,
                                             float* __restrict__ part)
{
  float local = 0.f;
  for (int v = blockIdx.x * 256 + threadIdx.x; v < T_ROWS * NVIS / 4; v += 256 * 256) {
    int col4 = (v & (NVIS / 4 - 1)) * 4;
    us4 a = ((const us4*)V)[v];
    float4 b = *(const float4*)&bv[col4];
    local += bf2f(a.x) * b.x + bf2f(a.y) * b.y + bf2f(a.z) * b.z + bf2f(a.w) * b.w;
  }
#pragma unroll
  for (int off = 32; off > 0; off >>= 1) local += __shfl_down(local, off, 64);
  __shared__ float red[4];
  if ((threadIdx.x & 63) == 0) red[threadIdx.x >> 6] = local;
  __syncthreads();
  if (threadIdx.x == 0) part[blockIdx.x] = red[0] + red[1] + red[2] + red[3];
}

// ---------------------------------------------------------------------------
// GEMM: C[M,N] = A[M,K] * B^T, B stored [N][K]. BN=128 fixed; BM, BK template.
// 512 threads = 8 waves (2 M x 4 N). Wave tile (BM/2) x 32.
// 3-buffer LDS pipeline, stage-ahead-1, counted vmcnt (never 0 mid-loop).
// MODE 0: C = bernoulli(sigmoid(z + bias)) bf16 {0,1}
// MODE 1: fpart[block] = sum softplus(z + bias)
// ---------------------------------------------------------------------------
template <int MODE, int BM, int BK>
__global__ void __launch_bounds__(512, 2)
rbm_gemm(const unsigned short* __restrict__ A, int lda,
         const unsigned short* __restrict__ B, int ldb,
         const float* __restrict__ bias,
         unsigned short* __restrict__ C, int ldc,
         float* __restrict__ fpart,
         int kdim, uint32_t phase)
{
  constexpr int MR = BM / 32;            // 16-row frags per wave (M)
  constexpr int CH = BK / 8;             // 16B chunks per LDS row
  constexpr int AJ = (BM * BK) / 4096;   // A loads per thread per stage
  constexpr int BJ = (128 * BK) / 4096;  // B loads per thread per stage
  constexpr int NL = AJ + BJ;            // loads in flight per stage
  constexpr int RSTEP = 512 / CH;        // rows per j step
  constexpr int ABYTES = BM * BK * 2;
  constexpr int BUFB = ABYTES + 128 * BK * 2;
  __shared__ __align__(16) char lds[3 * BUFB];

  const int tid  = threadIdx.x;
  const int lane = tid & 63;
  const int wv   = tid >> 6;
  const int wr   = wv >> 2;              // 0..1
  const int wc   = wv & 3;               // 0..3
  const int lr   = lane & 15;
  const int lq   = lane >> 4;

  // XCD-chunked tile swizzle (col-major chunks share W panels per XCD)
  const int gx = gridDim.x, gy = gridDim.y;
  const int nb = gx * gy;
  int orig = blockIdx.x + blockIdx.y * gx;
  int id = (orig & 7) * (nb >> 3) + (orig >> 3);
  int tx = id / gy;
  int ty = id - tx * gy;
  const int bm0 = ty * BM;
  const int bn0 = tx * 128;

  // staging map: LDS chunk L = j*512+tid -> row = L/CH, slot = L%CH;
  // source col-chunk = slot ^ (row & (CH-1));  (row & (CH-1)) is j-invariant.
  const int sRow = tid / CH;
  const int sCol = ((tid % CH) ^ (sRow & (CH - 1))) * 8;
  const unsigned short* gA = A + (size_t)(bm0 + sRow) * lda + sCol;
  const unsigned short* gB = B + (size_t)(bn0 + sRow) * ldb + sCol;

  auto STAGE = [&](int buf, int kt) {
    char* base = lds + buf * BUFB;
    const unsigned short* a0 = gA + (size_t)kt * BK;
    const unsigned short* b0 = gB + (size_t)kt * BK;
#pragma unroll
    for (int j = 0; j < AJ; ++j)
      __builtin_amdgcn_global_load_lds(AS1CV(a0 + (size_t)j * RSTEP * lda),
                                       AS3V(base + (j * 512 + tid) * 16), 16, 0, 0);
    char* bb = base + ABYTES;
#pragma unroll
    for (int j = 0; j < BJ; ++j)
      __builtin_amdgcn_global_load_lds(AS1CV(b0 + (size_t)j * RSTEP * ldb),
                                       AS3V(bb + (j * 512 + tid) * 16), 16, 0, 0);
  };

  f32x4 acc[MR][2];
#pragma unroll
  for (int m = 0; m < MR; ++m)
#pragma unroll
    for (int n = 0; n < 2; ++n) acc[m][n] = (f32x4)0.0f;

  const int nkt = kdim / BK;
  STAGE(0, 0);

  int cur = 0;
  for (int kt = 0; kt < nkt; ++kt) {
    int nxt = (cur == 2) ? 0 : cur + 1;
    if (kt + 1 < nkt) {
      STAGE(nxt, kt + 1);
      // wait: this iter's tile landed; next tile's NL loads stay in flight
      if constexpr (NL == 6) asm volatile("s_waitcnt vmcnt(6)" ::: "memory");
      else                   asm volatile("s_waitcnt vmcnt(4)" ::: "memory");
    } else {
      asm volatile("s_waitcnt vmcnt(0)" ::: "memory");
    }
    __builtin_amdgcn_sched_barrier(0);
    __builtin_amdgcn_s_barrier();
    __builtin_amdgcn_sched_barrier(0);

    char* base = lds + cur * BUFB;
    char* bb = base + ABYTES;
#pragma unroll
    for (int ks = 0; ks < BK / 32; ++ks) {
      short8 af[MR], bfr[2];
#pragma unroll
      for (int m = 0; m < MR; ++m) {
        int row = wr * (BM / 2) + m * 16 + lr;
        af[m] = *(const short8*)(base + row * (2 * BK) +
                                 (((ks * 4 + lq) ^ (row & (CH - 1))) * 16));
      }
#pragma unroll
      for (int n = 0; n < 2; ++n) {
        int row = wc * 32 + n * 16 + lr;
        bfr[n] = *(const short8*)(bb + row * (2 * BK) +
                                  (((ks * 4 + lq) ^ (row & (CH - 1))) * 16));
      }
#pragma unroll
      for (int m = 0; m < MR; ++m)
#pragma unroll
        for (int n = 0; n < 2; ++n)
          acc[m][n] = __builtin_amdgcn_mfma_f32_16x16x32_bf16(af[m], bfr[n], acc[m][n], 0, 0, 0);
    }
    cur = nxt;
  }

  if (MODE == 0) {
#pragma unroll
    for (int n = 0; n < 2; ++n) {
      int col = bn0 + wc * 32 + n * 16 + lr;
      float bv_ = bias[col];
#pragma unroll
      for (int m = 0; m < MR; ++m) {
        int row0 = bm0 + wr * (BM / 2) + m * 16 + lq * 4;
#pragma unroll
        for (int j = 0; j < 4; ++j) {
          int row = row0 + j;
          float z = acc[m][n][j] + bv_;
          float p = 1.0f / (1.0f + __expf(-z));
          float u = rng_u(phase, (uint32_t)(row * ldc + col));
          C[(size_t)row * ldc + col] = (u < p) ? (unsigned short)0x3F80 : (unsigned short)0;
        }
      }
    }
  } else {
    float local = 0.0f;
#pragma unroll
    for (int n = 0; n < 2; ++n) {
      int col = bn0 + wc * 32 + n * 16 + lr;
      float bv_ = bias[col];
#pragma unroll
      for (int m = 0; m < MR; ++m) {
#pragma unroll
        for (int j = 0; j < 4; ++j) {
          float z = acc[m][n][j] + bv_;
          local += fmaxf(z, 0.0f) + log1pf(expf(-fabsf(z)));
        }
      }
    }
#pragma unroll
    for (int off = 32; off > 0; off >>= 1) local += __shfl_down(local, off, 64);
    float* red = (float*)lds;
    __syncthreads();
    if (lane == 0) red[wv] = local;
    __syncthreads();
    if (tid == 0)
      fpart[id] = red[0] + red[1] + red[2] + red[3] + red[4] + red[5] + red[6] + red[7];
  }
}

// cost = (Sv + v.bv - Sx - x.bv) / T, double-precision reduce
__global__ void __launch_bounds__(256) finalize(const float* __restrict__ pFx,
                                                const float* __restrict__ pFv,
                                                const float* __restrict__ pXbv,
                                                const float* __restrict__ pVbv,
                                                float* __restrict__ out)
{
  __shared__ double red[256];
  double local = 0.0;
  int t = threadIdx.x;
  for (int i = t; i < 1024; i += 256) {
    if (i < 256)      local -= (double)pFx[i];
    else if (i < 512) local += (double)pFv[i - 256];
    else if (i < 768) local -= (double)pXbv[i - 512];
    else              local += (double)pVbv[i - 768];
  }
  red[t] = local;
  __syncthreads();
  for (int s = 128; s > 0; s >>= 1) {
    if (t < s) red[t] += red[t + s];
    __syncthreads();
  }
  if (t == 0) out[0] = (float)(red[0] / (double)T_ROWS);
}

extern "C" void kernel_launch(void* const* d_in, const int* in_sizes, int n_in,
                              void* d_out, int out_size, void* d_ws, size_t ws_size,
                              hipStream_t stream)
{
  const float* x  = (const float*)d_in[0];
  const float* w  = (const float*)d_in[1];
  const float* bh = (const float*)d_in[2];
  const float* bv = (const float*)d_in[3];

  char* ws = (char*)d_ws;
  unsigned short* Wb  = (unsigned short*)ws;                            // 16 MB
  unsigned short* WTb = (unsigned short*)(ws + (size_t)16777216);       // 16 MB
  unsigned short* Vb  = (unsigned short*)(ws + (size_t)33554432);       //  8 MB
  unsigned short* Hb  = (unsigned short*)(ws + (size_t)41943040);       //  4 MB
  float* pFx  = (float*)(ws + (size_t)46137344);
  float* pFv  = pFx + 256;
  float* pXbv = pFv + 256;
  float* pVbv = pXbv + 256;

  prep_w<<<dim3(NVIS / 64, NHID / 64), 256, 0, stream>>>(w, Wb, WTb);
  xcvt<<<(T_ROWS * NVIS / 4) / 256, 256, 0, stream>>>(x, Vb);

  // F(x): z = x @ W^T + bh  [1024 x 2048]; BM=64,BK=128 -> 16x16 = 256 blocks
  rbm_gemm<1, 64, 128><<<dim3(NHID / 128, T_ROWS / 64), 512, 0, stream>>>(
      Vb, NVIS, Wb, NVIS, bh, nullptr, 0, pFx, NVIS, 0u);
  bvdot<<<256, 256, 0, stream>>>(Vb, bv, pXbv);

  for (int k = 0; k < KGIBBS; ++k) {
    // h ~ Bern(sigmoid(v @ W^T + bh))  [1024 x 2048], 256 blocks
    rbm_gemm<0, 64, 128><<<dim3(NHID / 128, T_ROWS / 64), 512, 0, stream>>>(
        Vb, NVIS, Wb, NVIS, bh, Hb, NHID, nullptr, NVIS, (uint32_t)(2 * k));
    // v ~ Bern(sigmoid(h @ W + bv))    [1024 x 4096], 256 blocks
    rbm_gemm<0, 128, 64><<<dim3(NVIS / 128, T_ROWS / 128), 512, 0, stream>>>(
        Hb, NHID, WTb, NHID, bv, Vb, NVIS, nullptr, NHID, (uint32_t)(2 * k + 1));
  }

  rbm_gemm<1, 64, 128><<<dim3(NHID / 128, T_ROWS / 64), 512, 0, stream>>>(
      Vb, NVIS, Wb, NVIS, bh, nullptr, 0, pFv, NVIS, 0u);
  bvdot<<<256, 256, 0, stream>>>(Vb, bv, pVbv);

  finalize<<<1, 256, 0, stream>>>(pFx, pFv, pXbv, pVbv, (float*)d_out);
}